// Round 1
// baseline (353.147 us; speedup 1.0000x reference)
//
#include <hip/hip_runtime.h>

// KGL R7: 4-patch strip per block, fully-coalesced GAP streaming.
//  x: (8, 768, 768, 9) fp32. PSZ=24 -> p1=p2=32, N=1024, N*B=8192 patches.
//  Patch flat index j = b*1024 + pi*32 + pj.
//  Block handles patches j0..j0+3 (same b,pi; pj0..pj0+3): their row segments
//  are CONTIGUOUS in memory (4*216 floats = 216 float4 = 3456B per strip row),
//  so streaming waves issue full 64-lane 1KiB coalesced loads (vs 54/64 lanes
//  on 864B segments before).
//  Grid = 2048 blocks = exactly 8 blocks/CU (launch_bounds(256,8) forces
//  VGPR<=64) -> one fully-resident round, no tail.
//  ONE barrier per block (was 2 per patch): wg2 moved to streaming waves with
//  a per-column dense formulation (thread owns d[a] for a=0..8 of one column
//  bc, so the clip norm is thread-local -> no d_s cross-thread barrier).
//  Conv stays on VMEM/L1 (R5 lesson: LDS tee regressed), register-lean
//  immediate-consume form instead of pv[28] staging.

#define PSZ 24
#define NCH 9
#define HW 768
#define NPIX (PSZ*PSZ)              // 576
#define ROWF (PSZ*NCH)              // 216 floats per patch row
#define XROWF (HW*NCH)              // 6912 floats per image row
#define SP 4                        // patches per block (strip along pj)
#define SROWF (SP*ROWF)             // 864 floats per strip row (216 float4)
#define OUT2_OFF 663552

__global__ __launch_bounds__(256, 8) void kgl_kernel(
    const float* __restrict__ x,
    const float* __restrict__ conv_w,   // (3,3,9,9) HWIO flat, 729
    const float* __restrict__ conv_b,   // (9,)
    const float* __restrict__ dense_w,  // (9,81)
    const float* __restrict__ dense_b,  // (81,)
    float* __restrict__ out)
{
    __shared__ __align__(16) float cwA[732];    // wave0's conv_w copy (729 used)
    __shared__ __align__(16) float cwB[732];    // wave1's copy
    __shared__ __align__(16) float colA[SROWF]; // col sums rows 0..11  (wave2)
    __shared__ __align__(16) float colB[SROWF]; // col sums rows 12..23 (wave3)
    __shared__ float gapA[SP*NCH];
    __shared__ float gapB[SP*NCH];
    __shared__ float co_s[SP][81];

    const int j0  = blockIdx.x * SP;
    const int b   = j0 >> 10;
    const int rem = j0 & 1023;
    const int pi  = rem >> 5;
    const int pj0 = rem & 31;           // multiple of 4
    const int tid  = threadIdx.x;
    const int wid  = tid >> 6;
    const int lane = tid & 63;

    const size_t base = ((size_t)(b*HW + pi*PSZ) * HW + (size_t)pj0*PSZ) * NCH;
    const float* gbase = x + base;

    float cacc0 = 0.f, cacc1 = 0.f, cacc2 = 0.f, cacc3 = 0.f;

    // ---- Phase A (no barrier inside) ----
    if (wid < 2) {
        // conv waves: wave-local conv_w copy (no barrier needed before use)
        float* cw = wid ? cwB : cwA;
        #pragma unroll
        for (int i = 0; i < 3; ++i) {
            int e = lane + i*64;
            if (e < 182)
                reinterpret_cast<float4*>(cw)[e] =
                    reinterpret_cast<const float4*>(conv_w)[e];
        }
        if (lane == 0) cw[728] = conv_w[728];

        if (tid < 81) {
            const int oy = tid / 27;
            const int ox = (tid / 9) % 3;
            const int oc = tid % 9;
            const float bias = conv_b[oc];
            float ca[SP];
            #pragma unroll
            for (int p = 0; p < SP; ++p) {
                float acc = bias;
                #pragma unroll
                for (int ky = 0; ky < 3; ++ky) {
                    // 27 needed floats; 7 aligned float4 loads, last elem unused.
                    const float4* gp4 = reinterpret_cast<const float4*>(
                        gbase + (size_t)(oy*8 + ky)*XROWF + p*ROWF + ox*72);
                    #pragma unroll
                    for (int q = 0; q < 7; ++q) {
                        float4 v = gp4[q];
                        float vv[4] = {v.x, v.y, v.z, v.w};
                        #pragma unroll
                        for (int u = 0; u < 4; ++u) {
                            const int idx = q*4 + u;   // idx -> kx=idx/9, ic=idx%9
                            if (idx < 27)
                                acc += vv[u] * cw[(ky*3 + idx/9)*81 + (idx%9)*9 + oc];
                        }
                    }
                }
                co_s[p][tid] = acc;
                ca[p] = acc;
            }
            cacc0 = ca[0]; cacc1 = ca[1]; cacc2 = ca[2]; cacc3 = ca[3];
        }
    } else {
        // GAP streaming waves: fully coalesced strip rows (216 f4 contiguous).
        const int w  = wid - 2;
        const int r0 = w * 12;
        float4 a0 = make_float4(0.f,0.f,0.f,0.f);
        float4 a1 = a0, a2 = a0, a3 = a0;
        #pragma unroll
        for (int r = 0; r < 12; ++r) {
            const float4* row4 = reinterpret_cast<const float4*>(
                gbase + (size_t)(r0 + r)*XROWF);
            float4 v0 = row4[lane];
            float4 v1 = row4[lane + 64];
            float4 v2 = row4[lane + 128];
            a0.x += v0.x; a0.y += v0.y; a0.z += v0.z; a0.w += v0.w;
            a1.x += v1.x; a1.y += v1.y; a1.z += v1.z; a1.w += v1.w;
            a2.x += v2.x; a2.y += v2.y; a2.z += v2.z; a2.w += v2.w;
            if (lane < 24) {
                float4 v3 = row4[lane + 192];
                a3.x += v3.x; a3.y += v3.y; a3.z += v3.z; a3.w += v3.w;
            }
        }
        float* col = w ? colB : colA;
        reinterpret_cast<float4*>(col)[lane]       = a0;
        reinterpret_cast<float4*>(col)[lane + 64]  = a1;
        reinterpret_cast<float4*>(col)[lane + 128] = a2;
        if (lane < 24)
            reinterpret_cast<float4*>(col)[lane + 192] = a3;

        // wave-local fold: per patch p, channel ch, sum 24 pixel-columns
        if (lane < SP*NCH) {
            const int p  = lane / 9;
            const int ch = lane - p*9;
            float s = 0.f;
            #pragma unroll
            for (int i = 0; i < 24; ++i) s += col[p*ROWF + ch + 9*i];
            if (w) gapB[lane] = s; else gapA[lane] = s;
        }
    }
    __syncthreads();   // co_s, gapA, gapB valid

    // ---- Phase B: conv waves -> wg1; streaming waves -> wg2 ----
    if (wid < 2) {
        if (tid < 81) {
            const int oc = tid % 9;
            float ca[SP] = {cacc0, cacc1, cacc2, cacc3};
            #pragma unroll
            for (int p = 0; p < SP; ++p) {
                float n2 = 0.f;
                #pragma unroll
                for (int s = 0; s < 9; ++s) {
                    float v = co_s[p][s*9 + oc];
                    n2 += v*v;
                }
                float sc = 1.0f / fmaxf(sqrtf(n2), 1.0f);
                out[(size_t)(j0 + p)*81 + tid] = ca[p] * sc;
            }
        }
    } else {
        // wg2: thread k<36 owns (patch p, column bc); whole 9-row column in
        // registers -> thread-local clip norm, no extra barrier.
        const int k = tid - 128;
        if (k < SP*NCH) {
            const int p  = k / 9;
            const int bc = k - p*9;
            float g[9];
            #pragma unroll
            for (int c = 0; c < 9; ++c)
                g[c] = (gapA[p*9 + c] + gapB[p*9 + c]) * (1.0f/(float)NPIX);
            float d[9];
            float n2 = 0.f;
            #pragma unroll
            for (int a = 0; a < 9; ++a) {
                float acc = dense_b[a*9 + bc];
                #pragma unroll
                for (int c = 0; c < 9; ++c)
                    acc += g[c] * dense_w[c*81 + a*9 + bc];
                d[a] = acc;
                n2 += acc*acc;
            }
            float sc = 1.0f / fmaxf(sqrtf(n2), 1.0f);
            #pragma unroll
            for (int a = 0; a < 9; ++a)
                out[OUT2_OFF + (size_t)(j0 + p)*81 + a*9 + bc] = d[a] * sc;
        }
    }
}

extern "C" void kernel_launch(void* const* d_in, const int* in_sizes, int n_in,
                              void* d_out, int out_size, void* d_ws, size_t ws_size,
                              hipStream_t stream) {
    const float* x       = (const float*)d_in[0];
    const float* conv_w  = (const float*)d_in[1];
    const float* conv_b  = (const float*)d_in[2];
    const float* dense_w = (const float*)d_in[3];
    const float* dense_b = (const float*)d_in[4];
    float* out = (float*)d_out;

    kgl_kernel<<<2048, 256, 0, stream>>>(x, conv_w, conv_b, dense_w, dense_b, out);
}

// Round 2
// 266.306 us; speedup vs baseline: 1.3261x; 1.3261x over previous
//
#include <hip/hip_runtime.h>

// KGL R8: R7 strip structure, FIXED occupancy bound.
//  R7 post-mortem: __launch_bounds__(256,8) forced VGPR=32 -> massive scratch
//  spills (WRITE_SIZE 165MB vs 5.3MB real output; VALUBusy 4%). The strip
//  coalescing never got tested. R8 relaxes to (256,4): VGPR budget 128/wave,
//  4 blocks/CU, 2 resident rounds of the 2048-block grid. Streaming lanes have
//  36+ independent float4 loads in flight -> latency hidden at this occupancy.
//
//  Structure (unchanged from R7):
//  x: (8, 768, 768, 9) fp32. PSZ=24 -> p1=p2=32, N=1024, N*B=8192 patches.
//  Block handles 4 patches (same b,pi; consecutive pj): strip rows are
//  CONTIGUOUS (864 floats = 216 float4 = 3456B), so streaming waves issue
//  full 64-lane coalesced loads. ONE barrier per block. wg2 on streaming
//  waves with thread-local column norm. Conv on VMEM/L1 (R5 lesson: no LDS tee).

#define PSZ 24
#define NCH 9
#define HW 768
#define NPIX (PSZ*PSZ)              // 576
#define ROWF (PSZ*NCH)              // 216 floats per patch row
#define XROWF (HW*NCH)              // 6912 floats per image row
#define SP 4                        // patches per block (strip along pj)
#define SROWF (SP*ROWF)             // 864 floats per strip row (216 float4)
#define OUT2_OFF 663552

__global__ __launch_bounds__(256, 4) void kgl_kernel(
    const float* __restrict__ x,
    const float* __restrict__ conv_w,   // (3,3,9,9) HWIO flat, 729
    const float* __restrict__ conv_b,   // (9,)
    const float* __restrict__ dense_w,  // (9,81)
    const float* __restrict__ dense_b,  // (81,)
    float* __restrict__ out)
{
    __shared__ __align__(16) float cwA[732];    // wave0's conv_w copy (729 used)
    __shared__ __align__(16) float cwB[732];    // wave1's copy
    __shared__ __align__(16) float colA[SROWF]; // col sums rows 0..11  (wave2)
    __shared__ __align__(16) float colB[SROWF]; // col sums rows 12..23 (wave3)
    __shared__ float gapA[SP*NCH];
    __shared__ float gapB[SP*NCH];
    __shared__ float co_s[SP][81];

    const int j0  = blockIdx.x * SP;
    const int b   = j0 >> 10;
    const int rem = j0 & 1023;
    const int pi  = rem >> 5;
    const int pj0 = rem & 31;           // multiple of 4
    const int tid  = threadIdx.x;
    const int wid  = tid >> 6;
    const int lane = tid & 63;

    const size_t base = ((size_t)(b*HW + pi*PSZ) * HW + (size_t)pj0*PSZ) * NCH;
    const float* gbase = x + base;

    float cacc0 = 0.f, cacc1 = 0.f, cacc2 = 0.f, cacc3 = 0.f;

    // ---- Phase A (no barrier inside) ----
    if (wid < 2) {
        // conv waves: wave-local conv_w copy (no barrier needed before use)
        float* cw = wid ? cwB : cwA;
        #pragma unroll
        for (int i = 0; i < 3; ++i) {
            int e = lane + i*64;
            if (e < 182)
                reinterpret_cast<float4*>(cw)[e] =
                    reinterpret_cast<const float4*>(conv_w)[e];
        }
        if (lane == 0) cw[728] = conv_w[728];

        if (tid < 81) {
            const int oy = tid / 27;
            const int ox = (tid / 9) % 3;
            const int oc = tid % 9;
            const float bias = conv_b[oc];
            float ca[SP];
            #pragma unroll
            for (int p = 0; p < SP; ++p) {
                float acc = bias;
                #pragma unroll
                for (int ky = 0; ky < 3; ++ky) {
                    // 27 needed floats; 7 aligned float4 loads, last elem unused.
                    const float4* gp4 = reinterpret_cast<const float4*>(
                        gbase + (size_t)(oy*8 + ky)*XROWF + p*ROWF + ox*72);
                    #pragma unroll
                    for (int q = 0; q < 7; ++q) {
                        float4 v = gp4[q];
                        float vv[4] = {v.x, v.y, v.z, v.w};
                        #pragma unroll
                        for (int u = 0; u < 4; ++u) {
                            const int idx = q*4 + u;   // idx -> kx=idx/9, ic=idx%9
                            if (idx < 27)
                                acc += vv[u] * cw[(ky*3 + idx/9)*81 + (idx%9)*9 + oc];
                        }
                    }
                }
                co_s[p][tid] = acc;
                ca[p] = acc;
            }
            cacc0 = ca[0]; cacc1 = ca[1]; cacc2 = ca[2]; cacc3 = ca[3];
        }
    } else {
        // GAP streaming waves: fully coalesced strip rows (216 f4 contiguous).
        const int w  = wid - 2;
        const int r0 = w * 12;
        float4 a0 = make_float4(0.f,0.f,0.f,0.f);
        float4 a1 = a0, a2 = a0, a3 = a0;
        #pragma unroll
        for (int r = 0; r < 12; ++r) {
            const float4* row4 = reinterpret_cast<const float4*>(
                gbase + (size_t)(r0 + r)*XROWF);
            float4 v0 = row4[lane];
            float4 v1 = row4[lane + 64];
            float4 v2 = row4[lane + 128];
            a0.x += v0.x; a0.y += v0.y; a0.z += v0.z; a0.w += v0.w;
            a1.x += v1.x; a1.y += v1.y; a1.z += v1.z; a1.w += v1.w;
            a2.x += v2.x; a2.y += v2.y; a2.z += v2.z; a2.w += v2.w;
            if (lane < 24) {
                float4 v3 = row4[lane + 192];
                a3.x += v3.x; a3.y += v3.y; a3.z += v3.z; a3.w += v3.w;
            }
        }
        float* col = w ? colB : colA;
        reinterpret_cast<float4*>(col)[lane]       = a0;
        reinterpret_cast<float4*>(col)[lane + 64]  = a1;
        reinterpret_cast<float4*>(col)[lane + 128] = a2;
        if (lane < 24)
            reinterpret_cast<float4*>(col)[lane + 192] = a3;

        // wave-local fold: per patch p, channel ch, sum 24 pixel-columns
        if (lane < SP*NCH) {
            const int p  = lane / 9;
            const int ch = lane - p*9;
            float s = 0.f;
            #pragma unroll
            for (int i = 0; i < 24; ++i) s += col[p*ROWF + ch + 9*i];
            if (w) gapB[lane] = s; else gapA[lane] = s;
        }
    }
    __syncthreads();   // co_s, gapA, gapB valid

    // ---- Phase B: conv waves -> wg1; streaming waves -> wg2 ----
    if (wid < 2) {
        if (tid < 81) {
            const int oc = tid % 9;
            float ca[SP] = {cacc0, cacc1, cacc2, cacc3};
            #pragma unroll
            for (int p = 0; p < SP; ++p) {
                float n2 = 0.f;
                #pragma unroll
                for (int s = 0; s < 9; ++s) {
                    float v = co_s[p][s*9 + oc];
                    n2 += v*v;
                }
                float sc = 1.0f / fmaxf(sqrtf(n2), 1.0f);
                out[(size_t)(j0 + p)*81 + tid] = ca[p] * sc;
            }
        }
    } else {
        // wg2: thread k<36 owns (patch p, column bc); whole 9-row column in
        // registers -> thread-local clip norm, no extra barrier.
        const int k = tid - 128;
        if (k < SP*NCH) {
            const int p  = k / 9;
            const int bc = k - p*9;
            float g[9];
            #pragma unroll
            for (int c = 0; c < 9; ++c)
                g[c] = (gapA[p*9 + c] + gapB[p*9 + c]) * (1.0f/(float)NPIX);
            float d[9];
            float n2 = 0.f;
            #pragma unroll
            for (int a = 0; a < 9; ++a) {
                float acc = dense_b[a*9 + bc];
                #pragma unroll
                for (int c = 0; c < 9; ++c)
                    acc += g[c] * dense_w[c*81 + a*9 + bc];
                d[a] = acc;
                n2 += acc*acc;
            }
            float sc = 1.0f / fmaxf(sqrtf(n2), 1.0f);
            #pragma unroll
            for (int a = 0; a < 9; ++a)
                out[OUT2_OFF + (size_t)(j0 + p)*81 + a*9 + bc] = d[a] * sc;
        }
    }
}

extern "C" void kernel_launch(void* const* d_in, const int* in_sizes, int n_in,
                              void* d_out, int out_size, void* d_ws, size_t ws_size,
                              hipStream_t stream) {
    const float* x       = (const float*)d_in[0];
    const float* conv_w  = (const float*)d_in[1];
    const float* conv_b  = (const float*)d_in[2];
    const float* dense_w = (const float*)d_in[3];
    const float* dense_b = (const float*)d_in[4];
    float* out = (float*)d_out;

    kgl_kernel<<<2048, 256, 0, stream>>>(x, conv_w, conv_b, dense_w, dense_b, out);
}

// Round 4
// 241.190 us; speedup vs baseline: 1.4642x; 1.1041x over previous
//
#include <hip/hip_runtime.h>

// KGL R9 (resubmit — previous round was an infra failure, no data).
//  R6 geometry (per-patch blocks, proven best) + occupancy polish.
//  R7/R8 post-mortem: the 4-patch strip with 2048 blocks halved waves/CU
//  (16 vs ~32) and lost ~26us; coalescing upside was illusory (54-lane waves
//  on contiguous 864B segments already fetch ~96% useful bytes per line).
//  R9 reverts to 8192 blocks / 1 patch each and makes three lean changes:
//   1. conv: immediate-consume float4 (R8-verified) instead of pv[28] staging
//      -> ~28 fewer VGPR on the conv path.
//   2. wg2: thread-local column form (R8-verified) on 9 threads of wave 2
//      -> d_s and the second __syncthreads are gone (1 barrier per block).
//   3. __launch_bounds__(256,6): VGPR cap ~85 (both paths need <~50, no
//      spill risk), guarantees >=24 waves/CU for latency hiding.
//  Conv stays on VMEM/L1 (R5 lesson: LDS tee serialized conv behind stream).

#define PSZ 24
#define NCH 9
#define HW 768
#define NPIX (PSZ*PSZ)              // 576
#define ROWF (PSZ*NCH)              // 216 floats per patch row
#define ROWV4 54                    // 54 float4 per patch row
#define XROWF (HW*NCH)              // 6912 floats per image row
#define OUT2_OFF 663552

__global__ __launch_bounds__(256, 6) void kgl_kernel(
    const float* __restrict__ x,
    const float* __restrict__ conv_w,   // (3,3,9,9) HWIO flat, 729
    const float* __restrict__ conv_b,   // (9,)
    const float* __restrict__ dense_w,  // (9,81)
    const float* __restrict__ dense_b,  // (81,)
    float* __restrict__ out)
{
    __shared__ __align__(16) float cwA[732];   // wave0's conv_w copy (729 used)
    __shared__ __align__(16) float cwB[732];   // wave1's copy
    __shared__ __align__(16) float colA[ROWF]; // col sums rows 0..11  (wave2)
    __shared__ __align__(16) float colB[ROWF]; // col sums rows 12..23 (wave3)
    __shared__ float gapA[NCH];
    __shared__ float gapB[NCH];
    __shared__ float co_s[81];

    const int j   = blockIdx.x;
    const int b   = j >> 10;
    const int rem = j & 1023;
    const int pi  = rem >> 5;
    const int pj  = rem & 31;
    const int tid = threadIdx.x;

    const size_t base = ((size_t)(b*HW + pi*PSZ) * HW + (size_t)pj*PSZ) * NCH;
    const float* gbase = x + base;

    float conv_acc = 0.f;

    // ---- Phase A (no barrier inside) ----
    if (tid < 128) {
        // conv waves: wave-local conv_w copy (no barrier needed before use)
        float* cw = (tid < 64) ? cwA : cwB;
        const int lane = tid & 63;
        #pragma unroll
        for (int i = 0; i < 3; ++i) {
            int e = lane + i*64;
            if (e < 182)
                reinterpret_cast<float4*>(cw)[e] =
                    reinterpret_cast<const float4*>(conv_w)[e];
        }
        if (lane == 0) cw[728] = conv_w[728];

        if (tid < 81) {
            const int oy = tid / 27;
            const int ox = (tid / 9) % 3;
            const int oc = tid % 9;
            float acc = conv_b[oc];
            #pragma unroll
            for (int ky = 0; ky < 3; ++ky) {
                // 27 needed floats; 7 aligned float4 loads, immediate-consume
                // (no pv[] staging array -> ~28 fewer VGPR).
                const float4* gp4 = reinterpret_cast<const float4*>(
                    gbase + (size_t)(oy*8 + ky)*XROWF + (size_t)(ox*8)*NCH);
                #pragma unroll
                for (int q = 0; q < 7; ++q) {
                    float4 v = gp4[q];
                    float vv[4] = {v.x, v.y, v.z, v.w};
                    #pragma unroll
                    for (int u = 0; u < 4; ++u) {
                        const int idx = q*4 + u;   // idx -> kx=idx/9, ic=idx%9
                        if (idx < 27)
                            acc += vv[u] * cw[(ky*3 + idx/9)*81 + (idx%9)*9 + oc];
                    }
                }
            }
            co_s[tid] = acc;
            conv_acc = acc;
        }
    } else {
        // GAP waves: accumulate column sums straight from global (R6-proven).
        const int w  = (tid >= 192) ? 1 : 0;
        const int k  = tid & 63;
        const int r0 = w ? 12 : 0;
        if (k < ROWV4) {
            float4 acc = make_float4(0.f, 0.f, 0.f, 0.f);
            #pragma unroll
            for (int r = 0; r < 12; ++r) {
                float4 v = *reinterpret_cast<const float4*>(
                    gbase + (size_t)(r0 + r)*XROWF + (size_t)k*4);
                acc.x += v.x; acc.y += v.y; acc.z += v.z; acc.w += v.w;
            }
            reinterpret_cast<float4*>(w ? colB : colA)[k] = acc;
        }
        // wave-local fold 216 -> 9 channels
        if (k < NCH) {
            const float* col = w ? colB : colA;
            float s = 0.f;
            #pragma unroll
            for (int i = 0; i < 24; ++i) s += col[k + NCH*i];
            if (w) gapB[k] = s; else gapA[k] = s;
        }
    }
    __syncthreads();   // co_s, gapA, gapB valid  (the ONLY barrier)

    // ---- Phase B: wg1 on conv threads; wg2 thread-local on wave2 ----
    if (tid < 81) {
        const int oc = tid % 9;
        float n2 = 0.f;
        #pragma unroll
        for (int s = 0; s < 9; ++s) {
            float v = co_s[s*9 + oc];
            n2 += v*v;
        }
        float sc = 1.0f / fmaxf(sqrtf(n2), 1.0f);
        out[(size_t)j*81 + tid] = conv_acc * sc;
    } else if (tid >= 128 && tid < 128 + NCH) {
        // wg2: thread bc owns the full 9-row column of d -> thread-local norm,
        // no d_s, no second barrier (R8-verified formulation).
        const int bc = tid - 128;
        float g[9];
        #pragma unroll
        for (int c = 0; c < 9; ++c)
            g[c] = (gapA[c] + gapB[c]) * (1.0f/(float)NPIX);
        float d[9];
        float n2 = 0.f;
        #pragma unroll
        for (int a = 0; a < 9; ++a) {
            float acc = dense_b[a*9 + bc];
            #pragma unroll
            for (int c = 0; c < 9; ++c)
                acc += g[c] * dense_w[c*81 + a*9 + bc];
            d[a] = acc;
            n2 += acc*acc;
        }
        float sc = 1.0f / fmaxf(sqrtf(n2), 1.0f);
        #pragma unroll
        for (int a = 0; a < 9; ++a)
            out[OUT2_OFF + (size_t)j*81 + a*9 + bc] = d[a] * sc;
    }
}

extern "C" void kernel_launch(void* const* d_in, const int* in_sizes, int n_in,
                              void* d_out, int out_size, void* d_ws, size_t ws_size,
                              hipStream_t stream) {
    const float* x       = (const float*)d_in[0];
    const float* conv_w  = (const float*)d_in[1];
    const float* conv_b  = (const float*)d_in[2];
    const float* dense_w = (const float*)d_in[3];
    const float* dense_b = (const float*)d_in[4];
    float* out = (float*)d_out;

    kgl_kernel<<<8192, 256, 0, stream>>>(x, conv_w, conv_b, dense_w, dense_b, out);
}